// Round 3
// baseline (597.318 us; speedup 1.0000x reference)
//
#include <hip/hip_runtime.h>
#include <hip/hip_bf16.h>

#define IN_DIM   27000
#define ENC_DIM  768
#define LATENT   128
#define K_CODES  512
#define BATCH    256
#define NCF      9
#define CHUNKF   3000

// ---- d_out-region scratch (f32 slot offsets inside x_recon area, consumed
//      before k_recon overwrites it) ----
#define OS_FPART  0                             // [9][256][768] = 1,769,472
#define OS_F      (OS_FPART + NCF*BATCH*ENC_DIM) // [256][768]; end = 1,966,080 < 6,912,000

// ---- d_ws layout (float offsets), ~1.05 MB total ----
#define WS_Z      0                          // [256][128]
#define WS_QUANT  (WS_Z + BATCH*LATENT)      // [256][128]
#define WS_IDX    (WS_QUANT + BATCH*LATENT)  // int[256]
#define WS_VQPART (WS_IDX + BATCH)           // float[256]
#define WS_RECON  (WS_VQPART + BATCH)        // float[844] (reserve 1024)
#define WS_H      (WS_RECON + 1024)          // [256][768]
// end = WS_H + 196608 = 263,680 floats = 1,054,720 bytes

// ============ Kernel 1: F partials = x @ W_enc  (M=256, N=768, K split 9x3000) ============
__global__ __launch_bounds__(256) void k_f(const float* __restrict__ x,
                                           const float* __restrict__ Wenc,
                                           float* __restrict__ Fpart) {
    __shared__ float Xs[8][64];    // [k][m]
    __shared__ float Ws[8][128];   // [k][n]
    const int t = threadIdx.x;
    const int tx = t & 15, ty = t >> 4;
    const int m0 = blockIdx.x * 64;
    const int n0 = blockIdx.y * 128;
    const int kb0 = blockIdx.z * CHUNKF;

    float acc[4][8];
#pragma unroll
    for (int i = 0; i < 4; i++)
#pragma unroll
        for (int j = 0; j < 8; j++) acc[i][j] = 0.f;

    const int xa_row0 = t >> 3;   // 0..31
    const int xa_kk   = t & 7;    // 0..7
    const int wb_row  = t >> 5;   // 0..7
    const int wb_c4   = t & 31;   // 0..31

    for (int s = 0; s < CHUNKF / 8; s++) {
        const int kb = kb0 + s * 8;
        Xs[xa_kk][xa_row0]      = x[(size_t)(m0 + xa_row0)      * IN_DIM + kb + xa_kk];
        Xs[xa_kk][xa_row0 + 32] = x[(size_t)(m0 + xa_row0 + 32) * IN_DIM + kb + xa_kk];
        float4 wv = *(const float4*)(Wenc + (size_t)(kb + wb_row) * ENC_DIM + n0 + wb_c4 * 4);
        *(float4*)&Ws[wb_row][wb_c4 * 4] = wv;
        __syncthreads();

#pragma unroll
        for (int kk = 0; kk < 8; kk++) {
            float4 a4 = *(const float4*)&Xs[kk][ty * 4];
            float a[4] = {a4.x, a4.y, a4.z, a4.w};
            float b[8];
            *(float4*)&b[0] = *(const float4*)&Ws[kk][tx * 8];
            *(float4*)&b[4] = *(const float4*)&Ws[kk][tx * 8 + 4];
#pragma unroll
            for (int i = 0; i < 4; i++)
#pragma unroll
                for (int j = 0; j < 8; j++)
                    acc[i][j] = fmaf(a[i], b[j], acc[i][j]);
        }
        __syncthreads();
    }

#pragma unroll
    for (int i = 0; i < 4; i++) {
        const int row = m0 + ty * 4 + i;
#pragma unroll
        for (int j = 0; j < 8; j += 4) {
            float4 v = {acc[i][j], acc[i][j+1], acc[i][j+2], acc[i][j+3]};
            *(float4*)(Fpart + (size_t)blockIdx.z * (BATCH * ENC_DIM)
                       + (size_t)row * ENC_DIM + n0 + tx * 8 + j) = v;
        }
    }
}

// ============ Kernel 2: reduce F partials ============
__global__ __launch_bounds__(256) void k_fred(const float* __restrict__ Fpart,
                                              float* __restrict__ F) {
    const int o = blockIdx.x * 256 + threadIdx.x;   // < 196608
    float s = 0.f;
    for (int c = 0; c < NCF; c++) s += Fpart[(size_t)c * (BATCH * ENC_DIM) + o];
    F[o] = s;
}

// ============ Kernel 3: z = F @ W_lat + b_lat  (one block per batch row) ============
__global__ __launch_bounds__(128) void k_zb(const float* __restrict__ F,
                                            const float* __restrict__ Wlat,
                                            const float* __restrict__ blat,
                                            float* __restrict__ z) {
    __shared__ float Fs[ENC_DIM];
    const int b = blockIdx.x, t = threadIdx.x;
    for (int i = t; i < ENC_DIM; i += 128) Fs[i] = F[(size_t)b * ENC_DIM + i];
    __syncthreads();
    float acc = blat[t];
#pragma unroll 8
    for (int k = 0; k < ENC_DIM; k++)
        acc = fmaf(Fs[k], Wlat[(size_t)k * LATENT + t], acc);
    z[b * LATENT + t] = acc;
}

// ============ Kernel 4: VQ — distances, argmin, gather, vq partial ============
__global__ __launch_bounds__(256) void k_vq(const float* __restrict__ z,
                                            const float* __restrict__ cb,
                                            float* __restrict__ quant,
                                            int* __restrict__ idx_out,
                                            float* __restrict__ vqpart) {
    __shared__ float zs[LATENT];
    __shared__ float ds_[256];
    __shared__ int   is_[256];
    const int b = blockIdx.x, t = threadIdx.x;
    if (t < LATENT) zs[t] = z[b * LATENT + t];
    __syncthreads();

    float best_d = 3.4e38f; int best_i = 0;
#pragma unroll
    for (int rep = 0; rep < 2; rep++) {
        const int k = t + rep * 256;
        const float* e = cb + (size_t)k * LATENT;
        float acc = 0.f;
#pragma unroll 4
        for (int d = 0; d < LATENT; d += 4) {
            float4 ev = *(const float4*)(e + d);
            float d0 = zs[d]   - ev.x;
            float d1 = zs[d+1] - ev.y;
            float d2 = zs[d+2] - ev.z;
            float d3 = zs[d+3] - ev.w;
            acc += d0*d0 + d1*d1 + d2*d2 + d3*d3;
        }
        if (acc < best_d) { best_d = acc; best_i = k; }  // strict <: first min wins
    }
    ds_[t] = best_d; is_[t] = best_i;
    __syncthreads();
    for (int s = 128; s > 0; s >>= 1) {
        if (t < s) {
            float od = ds_[t+s]; int oi = is_[t+s];
            if (od < ds_[t] || (od == ds_[t] && oi < is_[t])) { ds_[t] = od; is_[t] = oi; }
        }
        __syncthreads();
    }
    const int best = is_[0];
    if (t == 0) idx_out[b] = best;

    float sq = 0.f;
    if (t < LATENT) {
        float q = cb[(size_t)best * LATENT + t];
        quant[b * LATENT + t] = q;
        float dd = q - zs[t];
        sq = dd * dd;
    }
    __syncthreads();
    ds_[t] = sq;
    __syncthreads();
    for (int s = 128; s > 0; s >>= 1) {
        if (t < s) ds_[t] += ds_[t+s];
        __syncthreads();
    }
    if (t == 0) vqpart[b] = ds_[0];
}

// ============ Kernel 5: h = relu(quant @ W_d1 + b_d1) ============
__global__ __launch_bounds__(256) void k_h(const float* __restrict__ quant,
                                           const float* __restrict__ Wd1,
                                           const float* __restrict__ bd1,
                                           float* __restrict__ h) {
    const int bid = blockIdx.x, t = threadIdx.x;
    const int row = bid / 3;
    const int col = (bid % 3) * 256 + t;
    float acc = bd1[col];
    const float* q = quant + row * LATENT;
#pragma unroll 8
    for (int k = 0; k < LATENT; k++)
        acc = fmaf(q[k], Wd1[(size_t)k * ENC_DIM + col], acc);
    h[(size_t)row * ENC_DIM + col] = fmaxf(acc, 0.f);
}

// ============ Kernel 6: x_recon = h @ W_d2 + b_d2, f32 out + fused loss ============
__global__ __launch_bounds__(256) void k_recon(const float* __restrict__ h,
                                               const float* __restrict__ Wd2,
                                               const float* __restrict__ bd2,
                                               const float* __restrict__ x,
                                               float* __restrict__ out,
                                               float* __restrict__ reconpart) {
    __shared__ float Hs[16][64];    // [k][m]
    __shared__ float Ws[16][128];   // [k][n]
    __shared__ float red[256];
    const int t = threadIdx.x;
    const int tx = t & 15, ty = t >> 4;
    const int m0 = blockIdx.x * 64;
    const int n0 = blockIdx.y * 128;

    float acc[4][8];
#pragma unroll
    for (int i = 0; i < 4; i++)
#pragma unroll
        for (int j = 0; j < 8; j++) acc[i][j] = 0.f;

    const int a_row = t >> 2, a_c4 = t & 3;
    const int b_row = t >> 5, b_c4 = t & 31;

    for (int k0 = 0; k0 < ENC_DIM; k0 += 16) {
        float4 av = *(const float4*)(h + (size_t)(m0 + a_row) * ENC_DIM + k0 + a_c4 * 4);
        Hs[a_c4*4+0][a_row] = av.x;
        Hs[a_c4*4+1][a_row] = av.y;
        Hs[a_c4*4+2][a_row] = av.z;
        Hs[a_c4*4+3][a_row] = av.w;

#pragma unroll
        for (int r = 0; r < 2; r++) {
            const int krow = k0 + b_row + r * 8;
            const int col  = n0 + b_c4 * 4;
            float4 bv;
            if (col + 3 < IN_DIM) {
                bv = *(const float4*)(Wd2 + (size_t)krow * IN_DIM + col);
            } else {
                bv.x = (col     < IN_DIM) ? Wd2[(size_t)krow * IN_DIM + col]     : 0.f;
                bv.y = (col + 1 < IN_DIM) ? Wd2[(size_t)krow * IN_DIM + col + 1] : 0.f;
                bv.z = (col + 2 < IN_DIM) ? Wd2[(size_t)krow * IN_DIM + col + 2] : 0.f;
                bv.w = (col + 3 < IN_DIM) ? Wd2[(size_t)krow * IN_DIM + col + 3] : 0.f;
            }
            *(float4*)&Ws[b_row + r*8][b_c4*4] = bv;
        }
        __syncthreads();

#pragma unroll
        for (int kk = 0; kk < 16; kk++) {
            float4 a4 = *(const float4*)&Hs[kk][ty*4];
            float a[4] = {a4.x, a4.y, a4.z, a4.w};
            float b[8];
            *(float4*)&b[0] = *(const float4*)&Ws[kk][tx*8];
            *(float4*)&b[4] = *(const float4*)&Ws[kk][tx*8+4];
#pragma unroll
            for (int i = 0; i < 4; i++)
#pragma unroll
                for (int j = 0; j < 8; j++)
                    acc[i][j] = fmaf(a[i], b[j], acc[i][j]);
        }
        __syncthreads();
    }

    float lsq = 0.f;
#pragma unroll
    for (int i = 0; i < 4; i++) {
        const int row = m0 + ty*4 + i;
        const int colbase = n0 + tx*8;
#pragma unroll
        for (int j = 0; j < 8; j++) {
            const int col = colbase + j;
            if (col < IN_DIM) {
                float r = acc[i][j] + bd2[col];
                acc[i][j] = r;
                float e = r - x[(size_t)row * IN_DIM + col];
                lsq += e * e;
            }
        }
        if (colbase + 7 < IN_DIM) {
#pragma unroll
            for (int j = 0; j < 8; j += 4) {
                float4 v = {acc[i][j], acc[i][j+1], acc[i][j+2], acc[i][j+3]};
                *(float4*)(out + (size_t)row * IN_DIM + colbase + j) = v;
            }
        } else {
            for (int j = 0; j < 8; j++) {
                const int col = colbase + j;
                if (col < IN_DIM) out[(size_t)row * IN_DIM + col] = acc[i][j];
            }
        }
    }

    red[t] = lsq;
    __syncthreads();
    for (int s = 128; s > 0; s >>= 1) {
        if (t < s) red[t] += red[t+s];
        __syncthreads();
    }
    if (t == 0) reconpart[blockIdx.y * 4 + blockIdx.x] = red[0];
}

// ============ Kernel 7: finalize losses + indices (f32) ============
__global__ __launch_bounds__(256) void k_final(const float* __restrict__ reconpart,
                                               const float* __restrict__ vqpart,
                                               const int* __restrict__ idx,
                                               float* __restrict__ out,
                                               long long obase) {
    __shared__ float red[256];
    const int t = threadIdx.x;
    float s = 0.f;
    for (int i = t; i < 844; i += 256) s += reconpart[i];
    red[t] = s;
    __syncthreads();
    for (int st = 128; st > 0; st >>= 1) {
        if (t < st) red[t] += red[t+st];
        __syncthreads();
    }
    const float recon_sum = red[0];
    __syncthreads();
    red[t] = vqpart[t];
    __syncthreads();
    for (int st = 128; st > 0; st >>= 1) {
        if (t < st) red[t] += red[t+st];
        __syncthreads();
    }
    const float vq_sum = red[0];
    if (t == 0) {
        float recon_loss = recon_sum / (float)((size_t)BATCH * IN_DIM);
        float vq_loss = 1.1f * vq_sum / (float)(BATCH * LATENT);
        out[obase + 0] = recon_loss + vq_loss;
        out[obase + 1] = vq_loss;
    }
    out[obase + 2 + t] = (float)idx[t];
}

extern "C" void kernel_launch(void* const* d_in, const int* in_sizes, int n_in,
                              void* d_out, int out_size, void* d_ws, size_t ws_size,
                              hipStream_t stream) {
    // Input mapping: setup_inputs() dict order, with size-keyed fallback.
    int ix = 0, iwe = 1, iwl = 2, ibl = 3, icb = 4, iwd1 = 5, ibd1 = 6, iwd2 = 7, ibd2 = 8;
    if (n_in == 9 && in_sizes[0] != BATCH * IN_DIM) {
        int p20[2] = {1, 7}, n20 = 0, p98[2] = {2, 5}, n98 = 0;
        for (int i = 0; i < 9; i++) {
            const int s = in_sizes[i];
            if      (s == BATCH * IN_DIM)    ix = i;
            else if (s == LATENT)            ibl = i;
            else if (s == K_CODES * LATENT)  icb = i;
            else if (s == ENC_DIM)           ibd1 = i;
            else if (s == IN_DIM)            ibd2 = i;
            else if (s == IN_DIM * ENC_DIM)  { if (n20 < 2) p20[n20++] = i; }
            else if (s == ENC_DIM * LATENT)  { if (n98 < 2) p98[n98++] = i; }
        }
        iwd2 = p20[0]; iwe = p20[1];   // alphabetical: W_d2 < W_enc
        iwd1 = p98[0]; iwl = p98[1];   // alphabetical: W_d1 < W_lat
    }
    const float* x    = (const float*)d_in[ix];
    const float* Wenc = (const float*)d_in[iwe];
    const float* Wlat = (const float*)d_in[iwl];
    const float* blat = (const float*)d_in[ibl];
    const float* cb   = (const float*)d_in[icb];
    const float* Wd1  = (const float*)d_in[iwd1];
    const float* bd1  = (const float*)d_in[ibd1];
    const float* Wd2  = (const float*)d_in[iwd2];
    const float* bd2  = (const float*)d_in[ibd2];

    float* out = (float*)d_out;

    // Big split-K scratch lives in the x_recon region of d_out (consumed by
    // k_fred/k_zb before k_recon overwrites it).
    float* Fpart = out + OS_FPART;
    float* F     = out + OS_F;

    float* ws        = (float*)d_ws;
    float* z         = ws + WS_Z;
    float* quant     = ws + WS_QUANT;
    int*   idxp      = (int*)(ws + WS_IDX);
    float* vqpart    = ws + WS_VQPART;
    float* reconpart = ws + WS_RECON;
    float* h         = ws + WS_H;

    const long long obase = (long long)out_size - 258;  // [.., total, vq, idx*256]

    k_f    <<<dim3(4, 6, NCF), 256, 0, stream>>>(x, Wenc, Fpart);
    k_fred <<<768, 256, 0, stream>>>(Fpart, F);
    k_zb   <<<BATCH, 128, 0, stream>>>(F, Wlat, blat, z);
    k_vq   <<<BATCH, 256, 0, stream>>>(z, cb, quant, idxp, vqpart);
    k_h    <<<768, 256, 0, stream>>>(quant, Wd1, bd1, h);
    k_recon<<<dim3(4, 211), 256, 0, stream>>>(h, Wd2, bd2, x, out, reconpart);
    k_final<<<1, 256, 0, stream>>>(reconpart, vqpart, idxp, out, obase);
}

// Round 4
// 218.901 us; speedup vs baseline: 2.7287x; 2.7287x over previous
//
#include <hip/hip_runtime.h>
#include <hip/hip_bf16.h>

#define IN_DIM   27000
#define ENC_DIM  768
#define LATENT   128
#define K_CODES  512
#define BATCH    256
#define KCH      27
#define CHUNK    1024
#define NRB      422            // k_recon blocks = ceil(27000/64)

// ---- d_out-region scratch (f32 slots inside x_recon area; consumed by
//      k_fred/k_zb before k_recon overwrites every element) ----
#define OS_FPART  0                               // [27][256][768] = 5,308,416
#define OS_F      (OS_FPART + KCH*BATCH*ENC_DIM)  // [256][768]; end 5,505,024 < 6,912,000

// ---- d_ws layout (float slots), ~661 KB ----
#define WS_Z      0                          // [256][128] f32
#define WS_QUANT  (WS_Z + BATCH*LATENT)      // [256][128] f32
#define WS_IDX    (WS_QUANT + BATCH*LATENT)  // int[256]
#define WS_VQPART (WS_IDX + BATCH)           // f32[256]
#define WS_RECON  (WS_VQPART + BATCH)        // f32[NRB] (reserve 1024)
#define WS_HBF    (WS_RECON + 1024)          // ushort[256*768] (98304 f32 slots)

typedef __attribute__((ext_vector_type(4))) float f32x4;
typedef __attribute__((ext_vector_type(8))) short short8x;

__device__ __forceinline__ unsigned short bf16_rne(float f) {
    unsigned u = __float_as_uint(f);
    unsigned r = 0x7FFFu + ((u >> 16) & 1u);
    return (unsigned short)((u + r) >> 16);
}
__device__ __forceinline__ float bf16_f32(unsigned short h) {
    return __uint_as_float(((unsigned)h) << 16);
}

// ============ Kernel 1: F partials = x @ W_enc via split-bf16 MFMA ============
// C[256,768], K=27000 split into 27 chunks of 1024. BM=64, BN=128.
// 4 waves (2x2), wave tile 32x64, 16x16x32 bf16 MFMA, 3-term (hh, hl, lh).
__global__ __launch_bounds__(256) void k_f_mfma(const float* __restrict__ x,
                                                const float* __restrict__ Wenc,
                                                float* __restrict__ Fpart) {
    __shared__ unsigned short Ah[64][40], Al[64][40];    // [m][k] pad 40
    __shared__ unsigned short Bh[128][40], Bl[128][40];  // [n][k] pad 40
    const int t  = threadIdx.x;
    const int m0 = blockIdx.x * 64;
    const int n0 = blockIdx.y * 128;
    const int c  = blockIdx.z;
    const int k_beg = c * CHUNK;
    const int k_end = min(IN_DIM, k_beg + CHUNK);
    const int ntile = (k_end - k_beg + 31) >> 5;

    const int lane = t & 63;
    const int wid  = t >> 6;
    const int wm = wid >> 1, wn = wid & 1;
    const int lrow = lane & 15, kg = lane >> 4;

    f32x4 acc[2][4];
#pragma unroll
    for (int mi = 0; mi < 2; mi++)
#pragma unroll
        for (int ni = 0; ni < 4; ni++) acc[mi][ni] = (f32x4){0.f, 0.f, 0.f, 0.f};

    const int sx_row = t >> 2, sx_kq = t & 3;   // x stage: 64 rows x 32 k
    const int sw_kr  = t >> 3, sw_nq = t & 7;   // W stage: 32 k x 128 n

    for (int ti = 0; ti < ntile; ti++) {
        const int k0 = k_beg + ti * 32;
        // ---- stage x tile -> Ah/Al ----
        {
            const float* xr = x + (size_t)(m0 + sx_row) * IN_DIM + k0;
#pragma unroll
            for (int hh = 0; hh < 2; hh++) {
                const int kf = sx_kq * 4 + hh * 16;
                float v[4];
                if (k0 + kf + 3 < k_end) {
                    float4 v4 = *(const float4*)(xr + kf);
                    v[0] = v4.x; v[1] = v4.y; v[2] = v4.z; v[3] = v4.w;
                } else {
#pragma unroll
                    for (int i = 0; i < 4; i++)
                        v[i] = (k0 + kf + i < k_end) ? xr[kf + i] : 0.f;
                }
#pragma unroll
                for (int i = 0; i < 4; i++) {
                    unsigned short hb = bf16_rne(v[i]);
                    Ah[sx_row][kf + i] = hb;
                    Al[sx_row][kf + i] = bf16_rne(v[i] - bf16_f32(hb));
                }
            }
        }
        // ---- stage W tile -> Bh/Bl (transposed) ----
        {
            const int kk = k0 + sw_kr;
            const float* wr = Wenc + (size_t)kk * ENC_DIM + n0;
            const bool kv = (kk < k_end);
#pragma unroll
            for (int hh = 0; hh < 4; hh++) {
                const int noff = 4 * sw_nq + 32 * hh;
                float v[4];
                if (kv) {
                    float4 v4 = *(const float4*)(wr + noff);
                    v[0] = v4.x; v[1] = v4.y; v[2] = v4.z; v[3] = v4.w;
                } else {
                    v[0] = v[1] = v[2] = v[3] = 0.f;
                }
#pragma unroll
                for (int i = 0; i < 4; i++) {
                    unsigned short hb = bf16_rne(v[i]);
                    Bh[noff + i][sw_kr] = hb;
                    Bl[noff + i][sw_kr] = bf16_rne(v[i] - bf16_f32(hb));
                }
            }
        }
        __syncthreads();

        short8x ah[2], al[2], bh[4], bl[4];
#pragma unroll
        for (int mi = 0; mi < 2; mi++) {
            const int m = wm * 32 + mi * 16 + lrow;
            ah[mi] = *(const short8x*)&Ah[m][kg * 8];
            al[mi] = *(const short8x*)&Al[m][kg * 8];
        }
#pragma unroll
        for (int ni = 0; ni < 4; ni++) {
            const int n = wn * 64 + ni * 16 + lrow;
            bh[ni] = *(const short8x*)&Bh[n][kg * 8];
            bl[ni] = *(const short8x*)&Bl[n][kg * 8];
        }
#pragma unroll
        for (int mi = 0; mi < 2; mi++)
#pragma unroll
            for (int ni = 0; ni < 4; ni++) {
                acc[mi][ni] = __builtin_amdgcn_mfma_f32_16x16x32_bf16(ah[mi], bh[ni], acc[mi][ni], 0, 0, 0);
                acc[mi][ni] = __builtin_amdgcn_mfma_f32_16x16x32_bf16(ah[mi], bl[ni], acc[mi][ni], 0, 0, 0);
                acc[mi][ni] = __builtin_amdgcn_mfma_f32_16x16x32_bf16(al[mi], bh[ni], acc[mi][ni], 0, 0, 0);
            }
        __syncthreads();
    }

    float* Fp = Fpart + (size_t)c * (BATCH * ENC_DIM);
#pragma unroll
    for (int mi = 0; mi < 2; mi++) {
        const int rowb = m0 + wm * 32 + mi * 16 + kg * 4;
#pragma unroll
        for (int ni = 0; ni < 4; ni++) {
            const int col = n0 + wn * 64 + ni * 16 + lrow;
#pragma unroll
            for (int r = 0; r < 4; r++)
                Fp[(size_t)(rowb + r) * ENC_DIM + col] = acc[mi][ni][r];
        }
    }
}

// ============ Kernel 2: reduce F partials ============
__global__ __launch_bounds__(256) void k_fred(const float* __restrict__ Fpart,
                                              float* __restrict__ F) {
    const int o = blockIdx.x * 256 + threadIdx.x;   // < 196608
    float s = 0.f;
    for (int c = 0; c < KCH; c++) s += Fpart[(size_t)c * (BATCH * ENC_DIM) + o];
    F[o] = s;
}

// ============ Kernel 3: z = F @ W_lat + b_lat ============
__global__ __launch_bounds__(128) void k_zb(const float* __restrict__ F,
                                            const float* __restrict__ Wlat,
                                            const float* __restrict__ blat,
                                            float* __restrict__ z) {
    __shared__ float Fs[ENC_DIM];
    const int b = blockIdx.x, t = threadIdx.x;
    for (int i = t; i < ENC_DIM; i += 128) Fs[i] = F[(size_t)b * ENC_DIM + i];
    __syncthreads();
    float acc = blat[t];
#pragma unroll 8
    for (int k = 0; k < ENC_DIM; k++)
        acc = fmaf(Fs[k], Wlat[(size_t)k * LATENT + t], acc);
    z[b * LATENT + t] = acc;
}

// ============ Kernel 4: VQ — distances, argmin, gather, vq partial ============
__global__ __launch_bounds__(256) void k_vq(const float* __restrict__ z,
                                            const float* __restrict__ cb,
                                            float* __restrict__ quant,
                                            int* __restrict__ idx_out,
                                            float* __restrict__ vqpart) {
    __shared__ float zs[LATENT];
    __shared__ float ds_[256];
    __shared__ int   is_[256];
    const int b = blockIdx.x, t = threadIdx.x;
    if (t < LATENT) zs[t] = z[b * LATENT + t];
    __syncthreads();

    float best_d = 3.4e38f; int best_i = 0;
#pragma unroll
    for (int rep = 0; rep < 2; rep++) {
        const int k = t + rep * 256;
        const float* e = cb + (size_t)k * LATENT;
        float acc = 0.f;
#pragma unroll 4
        for (int d = 0; d < LATENT; d += 4) {
            float4 ev = *(const float4*)(e + d);
            float d0 = zs[d]   - ev.x;
            float d1 = zs[d+1] - ev.y;
            float d2 = zs[d+2] - ev.z;
            float d3 = zs[d+3] - ev.w;
            acc += d0*d0 + d1*d1 + d2*d2 + d3*d3;
        }
        if (acc < best_d) { best_d = acc; best_i = k; }
    }
    ds_[t] = best_d; is_[t] = best_i;
    __syncthreads();
    for (int s = 128; s > 0; s >>= 1) {
        if (t < s) {
            float od = ds_[t+s]; int oi = is_[t+s];
            if (od < ds_[t] || (od == ds_[t] && oi < is_[t])) { ds_[t] = od; is_[t] = oi; }
        }
        __syncthreads();
    }
    const int best = is_[0];
    if (t == 0) idx_out[b] = best;

    float sq = 0.f;
    if (t < LATENT) {
        float q = cb[(size_t)best * LATENT + t];
        quant[b * LATENT + t] = q;
        float dd = q - zs[t];
        sq = dd * dd;
    }
    __syncthreads();
    ds_[t] = sq;
    __syncthreads();
    for (int s = 128; s > 0; s >>= 1) {
        if (t < s) ds_[t] += ds_[t+s];
        __syncthreads();
    }
    if (t == 0) vqpart[b] = ds_[0];
}

// ============ Kernel 5: h = relu(quant @ W_d1 + b_d1) -> bf16 ============
__global__ __launch_bounds__(256) void k_h(const float* __restrict__ quant,
                                           const float* __restrict__ Wd1,
                                           const float* __restrict__ bd1,
                                           unsigned short* __restrict__ hbf) {
    const int bid = blockIdx.x, t = threadIdx.x;
    const int row = bid / 3;
    const int col = (bid % 3) * 256 + t;
    float acc = bd1[col];
    const float* q = quant + row * LATENT;
#pragma unroll 8
    for (int k = 0; k < LATENT; k++)
        acc = fmaf(q[k], Wd1[(size_t)k * ENC_DIM + col], acc);
    hbf[(size_t)row * ENC_DIM + col] = bf16_rne(fmaxf(acc, 0.f));
}

// ============ Kernel 6: x_recon = h @ W_d2 + b_d2 (bf16 MFMA) + fused loss ============
// BM=256 (full batch), BN=64, K=768 (24 tiles). 4 waves, wave tile 64x64.
__global__ __launch_bounds__(256) void k_recon_mfma(const unsigned short* __restrict__ hbf,
                                                    const float* __restrict__ Wd2,
                                                    const float* __restrict__ bd2,
                                                    const float* __restrict__ x,
                                                    float* __restrict__ out,
                                                    float* __restrict__ reconpart) {
    __shared__ unsigned short Ahs[256][40];   // [m][k] pad 40
    __shared__ unsigned short Bts[64][40];    // [n][k] pad 40
    __shared__ float red[256];
    const int t  = threadIdx.x;
    const int n0 = blockIdx.x * 64;
    const int lane = t & 63;
    const int wid  = t >> 6;
    const int lrow = lane & 15, kg = lane >> 4;

    f32x4 acc[4][4];
#pragma unroll
    for (int mi = 0; mi < 4; mi++)
#pragma unroll
        for (int ni = 0; ni < 4; ni++) acc[mi][ni] = (f32x4){0.f, 0.f, 0.f, 0.f};

    const int sa_row = t >> 2, sa_q = t & 3;    // A: 4 passes x 64 rows
    const int sb_kr  = t >> 3, sb_nq = t & 7;   // B: 32 k x 64 n

    for (int kt = 0; kt < ENC_DIM / 32; kt++) {
        const int k0 = kt * 32;
        // ---- stage h (already bf16) ----
#pragma unroll
        for (int p = 0; p < 4; p++) {
            const int row = sa_row + p * 64;
            *(short8x*)&Ahs[row][sa_q * 8] =
                *(const short8x*)(hbf + (size_t)row * ENC_DIM + k0 + sa_q * 8);
        }
        // ---- stage W_d2 (f32 -> bf16, transposed) ----
        {
            const float* wr = Wd2 + (size_t)(k0 + sb_kr) * IN_DIM + n0;
#pragma unroll
            for (int hh = 0; hh < 2; hh++) {
                const int noff = 4 * sb_nq + 32 * hh;
                float v[4];
                if (n0 + noff + 3 < IN_DIM) {
                    float4 v4 = *(const float4*)(wr + noff);
                    v[0] = v4.x; v[1] = v4.y; v[2] = v4.z; v[3] = v4.w;
                } else {
#pragma unroll
                    for (int i = 0; i < 4; i++)
                        v[i] = (n0 + noff + i < IN_DIM) ? wr[noff + i] : 0.f;
                }
#pragma unroll
                for (int i = 0; i < 4; i++)
                    Bts[noff + i][sb_kr] = bf16_rne(v[i]);
            }
        }
        __syncthreads();

        short8x a[4], b[4];
#pragma unroll
        for (int mi = 0; mi < 4; mi++)
            a[mi] = *(const short8x*)&Ahs[wid * 64 + mi * 16 + lrow][kg * 8];
#pragma unroll
        for (int ni = 0; ni < 4; ni++)
            b[ni] = *(const short8x*)&Bts[ni * 16 + lrow][kg * 8];
#pragma unroll
        for (int mi = 0; mi < 4; mi++)
#pragma unroll
            for (int ni = 0; ni < 4; ni++)
                acc[mi][ni] = __builtin_amdgcn_mfma_f32_16x16x32_bf16(a[mi], b[ni], acc[mi][ni], 0, 0, 0);
        __syncthreads();
    }

    float lsq = 0.f;
#pragma unroll
    for (int mi = 0; mi < 4; mi++) {
        const int rowb = wid * 64 + mi * 16 + kg * 4;
#pragma unroll
        for (int ni = 0; ni < 4; ni++) {
            const int col = n0 + ni * 16 + lrow;
            if (col < IN_DIM) {
                const float bb = bd2[col];
#pragma unroll
                for (int r = 0; r < 4; r++) {
                    const int row = rowb + r;
                    float v = acc[mi][ni][r] + bb;
                    float e = v - x[(size_t)row * IN_DIM + col];
                    lsq += e * e;
                    out[(size_t)row * IN_DIM + col] = v;
                }
            }
        }
    }

    red[t] = lsq;
    __syncthreads();
    for (int s = 128; s > 0; s >>= 1) {
        if (t < s) red[t] += red[t + s];
        __syncthreads();
    }
    if (t == 0) reconpart[blockIdx.x] = red[0];
}

// ============ Kernel 7: finalize losses + indices (f32) ============
__global__ __launch_bounds__(256) void k_final(const float* __restrict__ reconpart,
                                               const float* __restrict__ vqpart,
                                               const int* __restrict__ idx,
                                               float* __restrict__ out,
                                               long long obase) {
    __shared__ float red[256];
    const int t = threadIdx.x;
    float s = 0.f;
    for (int i = t; i < NRB; i += 256) s += reconpart[i];
    red[t] = s;
    __syncthreads();
    for (int st = 128; st > 0; st >>= 1) {
        if (t < st) red[t] += red[t + st];
        __syncthreads();
    }
    const float recon_sum = red[0];
    __syncthreads();
    red[t] = vqpart[t];
    __syncthreads();
    for (int st = 128; st > 0; st >>= 1) {
        if (t < st) red[t] += red[t + st];
        __syncthreads();
    }
    const float vq_sum = red[0];
    if (t == 0) {
        float recon_loss = recon_sum / (float)((size_t)BATCH * IN_DIM);
        float vq_loss = 1.1f * vq_sum / (float)(BATCH * LATENT);
        out[obase + 0] = recon_loss + vq_loss;
        out[obase + 1] = vq_loss;
    }
    out[obase + 2 + t] = (float)idx[t];
}

extern "C" void kernel_launch(void* const* d_in, const int* in_sizes, int n_in,
                              void* d_out, int out_size, void* d_ws, size_t ws_size,
                              hipStream_t stream) {
    int ix = 0, iwe = 1, iwl = 2, ibl = 3, icb = 4, iwd1 = 5, ibd1 = 6, iwd2 = 7, ibd2 = 8;
    if (n_in == 9 && in_sizes[0] != BATCH * IN_DIM) {
        int p20[2] = {1, 7}, n20 = 0, p98[2] = {2, 5}, n98 = 0;
        for (int i = 0; i < 9; i++) {
            const int s = in_sizes[i];
            if      (s == BATCH * IN_DIM)    ix = i;
            else if (s == LATENT)            ibl = i;
            else if (s == K_CODES * LATENT)  icb = i;
            else if (s == ENC_DIM)           ibd1 = i;
            else if (s == IN_DIM)            ibd2 = i;
            else if (s == IN_DIM * ENC_DIM)  { if (n20 < 2) p20[n20++] = i; }
            else if (s == ENC_DIM * LATENT)  { if (n98 < 2) p98[n98++] = i; }
        }
        iwd2 = p20[0]; iwe = p20[1];
        iwd1 = p98[0]; iwl = p98[1];
    }
    const float* x    = (const float*)d_in[ix];
    const float* Wenc = (const float*)d_in[iwe];
    const float* Wlat = (const float*)d_in[iwl];
    const float* blat = (const float*)d_in[ibl];
    const float* cb   = (const float*)d_in[icb];
    const float* Wd1  = (const float*)d_in[iwd1];
    const float* bd1  = (const float*)d_in[ibd1];
    const float* Wd2  = (const float*)d_in[iwd2];
    const float* bd2  = (const float*)d_in[ibd2];

    float* out = (float*)d_out;
    float* Fpart = out + OS_FPART;
    float* F     = out + OS_F;

    float* ws            = (float*)d_ws;
    float* z             = ws + WS_Z;
    float* quant         = ws + WS_QUANT;
    int*   idxp          = (int*)(ws + WS_IDX);
    float* vqpart        = ws + WS_VQPART;
    float* reconpart     = ws + WS_RECON;
    unsigned short* hbf  = (unsigned short*)(ws + WS_HBF);

    const long long obase = (long long)out_size - 258;

    k_f_mfma    <<<dim3(4, 6, KCH), 256, 0, stream>>>(x, Wenc, Fpart);
    k_fred      <<<768, 256, 0, stream>>>(Fpart, F);
    k_zb        <<<BATCH, 128, 0, stream>>>(F, Wlat, blat, z);
    k_vq        <<<BATCH, 256, 0, stream>>>(z, cb, quant, idxp, vqpart);
    k_h         <<<768, 256, 0, stream>>>(quant, Wd1, bd1, hbf);
    k_recon_mfma<<<NRB, 256, 0, stream>>>(hbf, Wd2, bd2, x, out, reconpart);
    k_final     <<<1, 256, 0, stream>>>(reconpart, vqpart, idxp, out, obase);
}